// Round 2
// baseline (2634.591 us; speedup 1.0000x reference)
//
#include <hip/hip_runtime.h>
#include <hip/hip_bf16.h>

typedef __hip_bfloat16 bf16;
typedef __attribute__((ext_vector_type(8))) short bf16x8;
typedef __attribute__((ext_vector_type(4))) float f32x4;

// ---- dims ----
#define BB   2
#define LL   1024
#define DMm  1024
#define DIx  2048
#define E2   4096
#define DRr  64

// ---- workspace: static device globals (no d_ws dependence; every buffer fully
// rewritten each call before use, so graph replay is deterministic) ----
__device__ __align__(16) bf16  g_hs_bf16[(long)BB*LL*DMm];        // (b,l,d) bf16
__device__ __align__(16) bf16  g_win_bf16[(long)E2*DMm];          // (e,d)
__device__ __align__(16) float g_xz[(long)BB*E2*LL];              // (b,e,l) fp32
__device__ __align__(16) float g_xf_t[(long)BB*LL*DIx];           // fwd conv'd x, (b,l,d)
__device__ __align__(16) float g_xb_t[(long)BB*LL*DIx];           // bwd conv'd x, (b,l',d)
__device__ __align__(16) float g_z_t[(long)BB*LL*DIx];            // z transposed (b,l,d)
__device__ __align__(16) bf16  g_xf_bf16[(long)BB*LL*DIx];
__device__ __align__(16) bf16  g_xb_bf16[(long)BB*LL*DIx];
__device__ __align__(16) bf16  g_wxp_f[96*DIx], g_wxp_b[96*DIx];
__device__ __align__(16) float g_xdbl_f[(long)BB*LL*96], g_xdbl_b[(long)BB*LL*96];
__device__ __align__(16) bf16  g_xdbl_f_bf16[(long)BB*LL*96], g_xdbl_b_bf16[(long)BB*LL*96];
__device__ __align__(16) bf16  g_wdt_f[DIx*DRr], g_wdt_b[DIx*DRr];
__device__ __align__(16) float g_delta_f[(long)BB*LL*DIx], g_delta_b[(long)BB*LL*DIx]; // softplus'd
__device__ __align__(16) float g_out_f[(long)BB*LL*DIx], g_out_b[(long)BB*LL*DIx];     // gated branch outs
__device__ __align__(16) float2 g_fftA[(long)BB*LL*DIx];          // (b,l,d) complex
__device__ __align__(16) bf16  g_xc[(long)BB*LL*E2];              // conv input (b,l,ch) bf16
__device__ __align__(16) bf16  g_wc[(long)5*E2*E2];               // conv W repacked [t][o][i] bf16
__device__ __align__(16) float g_conv_out[(long)BB*E2*LL];        // (b,o,l)
__device__ __align__(16) float g_v[(long)BB*LL*DIx];              // (b,l,d)
__device__ float g_zmax[BB*DIx], g_mu[BB*DIx], g_rsig[BB*DIx];
__device__ __align__(16) bf16  g_y_bf16[(long)BB*LL*DIx];         // (b,l,d)
__device__ __align__(16) bf16  g_wout_bf16[(long)DMm*DIx];

__device__ __forceinline__ float siluf(float x) { return x / (1.f + __expf(-x)); }

// ---------------- casts ----------------
__global__ void cast_all(const float* hs, const float* win, const float* wout,
                         const float* wxpf, const float* wxpb,
                         const float* wdtf, const float* wdtb)
{
  long t0 = (long)blockIdx.x*256 + threadIdx.x;
  long st = (long)gridDim.x*256;
  for (long i=t0; i<(long)BB*LL*DMm; i+=st) g_hs_bf16[i]  = __float2bfloat16(hs[i]);
  for (long i=t0; i<(long)E2*DMm;    i+=st) g_win_bf16[i] = __float2bfloat16(win[i]);
  for (long i=t0; i<(long)DMm*DIx;   i+=st) g_wout_bf16[i]= __float2bfloat16(wout[i]);
  for (long i=t0; i<(long)96*DIx;    i+=st) { g_wxp_f[i]=__float2bfloat16(wxpf[i]); g_wxp_b[i]=__float2bfloat16(wxpb[i]); }
  for (long i=t0; i<(long)DIx*DRr;   i+=st) { g_wdt_f[i]=__float2bfloat16(wdtf[i]); g_wdt_b[i]=__float2bfloat16(wdtb[i]); }
}

__global__ void repack_wc(const float* wc)   // (o,i,t) fp32 -> [t][o][i] bf16
{
  const long NM = (long)E2*E2;
  long t0 = (long)blockIdx.x*256 + threadIdx.x;
  long st = (long)gridDim.x*256;
  for (long i=t0; i<NM; i+=st) {
    const float* p = wc + i*5;
    #pragma unroll
    for (int t=0;t<5;t++) g_wc[(long)t*NM + i] = __float2bfloat16(p[t]);
  }
}

__global__ void zero_xdbl() {
  long n = (long)BB*LL*96;
  for (long i=(long)blockIdx.x*256+threadIdx.x; i<n; i+=(long)gridDim.x*256) { g_xdbl_f[i]=0.f; g_xdbl_b[i]=0.f; }
}
__global__ void cast_xdbl() {
  long n = (long)BB*LL*96;
  for (long i=(long)blockIdx.x*256+threadIdx.x; i<n; i+=(long)gridDim.x*256) {
    g_xdbl_f_bf16[i]=__float2bfloat16(g_xdbl_f[i]);
    g_xdbl_b_bf16[i]=__float2bfloat16(g_xdbl_b[i]);
  }
}

// ---------------- generic NT MFMA GEMM: C[m][n] = sum_k A[m][k]*B[n][k] ----------------
// BM=BN=128, BK=64, 4 waves (64x64 each). Buffers bound at compile time per ID.
template<int ID>
__global__ __launch_bounds__(256) void gemm_nt(float* Cext, const float* bias)
{
  constexpr int M    = (ID==0||ID==5) ? 4096 : 1024;
  constexpr int N    = (ID==0) ? 1024 : (ID==1||ID==2) ? 96 : (ID==3||ID==4) ? 2048 : 1024;
  constexpr int K    = (ID==0) ? 1024 : (ID==1||ID==2) ? 2048 : (ID==3||ID==4) ? 64 : (ID==5) ? 4096 : 2048;
  constexpr int LDA  = (ID==0) ? 1024 : (ID==1||ID==2) ? 2048 : (ID==3||ID==4) ? 96 : (ID==5) ? 4096 : 2048;
  constexpr int LDB  = (ID==0) ? 1024 : (ID==1||ID==2) ? 2048 : (ID==3||ID==4) ? 64 : (ID==5) ? 4096 : 2048;
  constexpr int LDC  = (ID==1||ID==2) ? 96 : (ID==3||ID==4) ? 2048 : 1024;
  constexpr int BROWS= (ID==1||ID==2) ? 96 : (ID==3||ID==4) ? 2048 : 1024;
  constexpr int TAPS = (ID==5) ? 5 : 1;
  constexpr int SPLITK = (ID==1||ID==2) ? 16 : 1;
  constexpr bool SP  = (ID==3||ID==4);
  constexpr long SA  = (ID==0||ID==5) ? 0 : (ID==3||ID==4) ? (long)LL*96 : (long)LL*DIx;
  constexpr long SB  = (ID==0) ? (long)LL*DMm : (ID==5) ? (long)LL*E2 : 0;
  constexpr long SC  = (ID==0||ID==5) ? (long)E2*LL : (ID==1||ID==2) ? (long)LL*96 :
                       (ID==3||ID==4) ? (long)LL*DIx : (long)LL*DMm;
  constexpr int KS   = K / SPLITK;

  const bf16* Abase; const bf16* Bbase; float* Cbase;
  if constexpr (ID==0) { Abase=g_win_bf16;     Bbase=g_hs_bf16; Cbase=g_xz; }
  else if constexpr (ID==1) { Abase=g_xf_bf16; Bbase=g_wxp_f;   Cbase=g_xdbl_f; }
  else if constexpr (ID==2) { Abase=g_xb_bf16; Bbase=g_wxp_b;   Cbase=g_xdbl_b; }
  else if constexpr (ID==3) { Abase=g_xdbl_f_bf16; Bbase=g_wdt_f; Cbase=g_delta_f; }
  else if constexpr (ID==4) { Abase=g_xdbl_b_bf16; Bbase=g_wdt_b; Cbase=g_delta_b; }
  else if constexpr (ID==5) { Abase=g_wc;      Bbase=g_xc;      Cbase=g_conv_out; }
  else                      { Abase=g_y_bf16;  Bbase=g_wout_bf16; Cbase=Cext; }

  const int tid  = threadIdx.x;
  const int zi   = blockIdx.z;
  const int bbat = zi / SPLITK;
  const int ksp  = zi % SPLITK;
  const bf16* Ab = Abase + (long)bbat*SA;
  const bf16* Bb = Bbase + (long)bbat*SB;
  float* Cb = Cbase + (long)bbat*SC;

  __shared__ bf16 As[128][72];
  __shared__ bf16 Bs[128][72];
  const int m0 = blockIdx.y*128, n0 = blockIdx.x*128;
  const int wave = tid>>6, lane = tid&63;
  const int wr = (wave>>1)*64, wc = (wave&1)*64;
  const int lr = lane&15, lk = (lane>>4)*8;
  const int srow = tid>>3, sch = (tid&7)*8;

  f32x4 acc[4][4];
  #pragma unroll
  for (int i=0;i<4;i++)
    #pragma unroll
    for (int j=0;j<4;j++) acc[i][j] = (f32x4){0.f,0.f,0.f,0.f};

  for (int tap=0; tap<TAPS; ++tap) {
    const bf16* At = Ab + (long)tap*((long)M*K);
    const int roff = (TAPS>1) ? (tap-2) : 0;
    for (int kt=0; kt<KS; kt+=64) {
      const int k0 = ksp*KS + kt;
      __syncthreads();
      #pragma unroll
      for (int it=0; it<4; ++it) {
        int rr = srow + it*32;
        int mg = m0 + rr;
        uint4 va = make_uint4(0u,0u,0u,0u);
        if (mg < M) va = *(const uint4*)(At + (long)mg*LDA + k0 + sch);
        *(uint4*)&As[rr][sch] = va;
        int ng = n0 + rr + roff;
        uint4 vb = make_uint4(0u,0u,0u,0u);
        if (ng >= 0 && ng < BROWS) vb = *(const uint4*)(Bb + (long)ng*LDB + k0 + sch);
        *(uint4*)&Bs[rr][sch] = vb;
      }
      __syncthreads();
      #pragma unroll
      for (int kk=0; kk<2; ++kk) {
        bf16x8 af[4], bfr[4];
        #pragma unroll
        for (int i=0;i<4;i++) {
          af[i]  = *(const bf16x8*)&As[wr + i*16 + lr][kk*32 + lk];
          bfr[i] = *(const bf16x8*)&Bs[wc + i*16 + lr][kk*32 + lk];
        }
        #pragma unroll
        for (int i=0;i<4;i++)
          #pragma unroll
          for (int j=0;j<4;j++)
            acc[i][j] = __builtin_amdgcn_mfma_f32_16x16x32_bf16(af[i], bfr[j], acc[i][j], 0,0,0);
      }
    }
  }

  const int rg = (lane>>4)*4;   // C/D: col=lane&15, row=(lane>>4)*4+reg
  #pragma unroll
  for (int i=0;i<4;i++) {
    #pragma unroll
    for (int j=0;j<4;j++) {
      int n = n0 + wc + j*16 + lr;
      if (n < N) {
        #pragma unroll
        for (int r=0;r<4;r++) {
          int m = m0 + wr + i*16 + rg + r;
          if (m < M) {
            float v = acc[i][j][r];
            if constexpr (SP) { v += bias[n]; v = (v > 20.f) ? v : log1pf(__expf(v)); }
            if constexpr (SPLITK > 1) atomicAdd(&Cb[(long)m*LDC + n], v);
            else Cb[(long)m*LDC + n] = v;
          }
        }
      }
    }
  }
}

// ---------------- depthwise causal conv + silu + transpose; also z transpose ----------------
// grid (L/64, D/64, B*3): mode 0=fwd conv, 1=bwd(reversed) conv, 2=z copy
__global__ __launch_bounds__(256) void k3_kernel(const float* cwf, const float* cbf,
                                                 const float* cwb, const float* cbb)
{
  int lt = blockIdx.x*64, dt = blockIdx.y*64;
  int b = blockIdx.z / 3, mode = blockIdx.z % 3;
  __shared__ float tile[64][68];
  int tid = threadIdx.x;
  for (int idx = tid; idx < 64*68; idx += 256) {
    int dl = idx / 68, c = idx % 68;
    float v = 0.f;
    if (c < 67) {
      int j = lt - 3 + c;                    // branch-position index
      if (j >= 0) {
        int gl = (mode==1) ? (LL-1-j) : j;   // reversed sequence for bwd branch
        int ch = (mode==2) ? (DIx + dt + dl) : (dt + dl);
        v = g_xz[((long)b*E2 + ch)*LL + gl];
      }
    }
    tile[dl][c] = v;
  }
  __syncthreads();
  int lloc = tid >> 2;
  int dseg = (tid & 3) * 16;
  long base = ((long)b*LL + (lt + lloc))*DIx + dt + dseg;
  if (mode == 2) {
    for (int jj=0; jj<16; ++jj) g_z_t[base+jj] = tile[dseg+jj][lloc+3];
  } else {
    const float* cw = mode ? cwb : cwf;
    const float* cb = mode ? cbb : cbf;
    float* xt = mode ? g_xb_t : g_xf_t;
    bf16*  xq = mode ? g_xb_bf16 : g_xf_bf16;
    for (int jj=0; jj<16; ++jj) {
      int dg = dt + dseg + jj;
      float a = cb[dg];
      #pragma unroll
      for (int t=0;t<4;t++) a = fmaf(cw[dg*4+t], tile[dseg+jj][lloc+t], a);
      float s = siluf(a);
      xt[base+jj] = s;
      xq[base+jj] = __float2bfloat16(s);
    }
  }
}

// ---------------- selective scan (both branches), 16 n-lanes per (b,d) ----------------
__global__ __launch_bounds__(256) void scan_kernel(const float* alog_f, const float* dd_f,
                                                   const float* alog_b, const float* dd_b)
{
  int br = blockIdx.z, b = blockIdx.y;
  int d0 = blockIdx.x * 16;
  int tid = threadIdx.x;
  int n = tid & 15, dl = tid >> 4;
  int d = d0 + dl;
  const float* delta = (br ? g_delta_b : g_delta_f) + (long)b*LL*DIx;
  const float* xt    = (br ? g_xb_t    : g_xf_t)    + (long)b*LL*DIx;
  const float* xdbl  = (br ? g_xdbl_b  : g_xdbl_f)  + (long)b*LL*96;
  float* outp        = (br ? g_out_b   : g_out_f)   + (long)b*LL*DIx;
  const float* Alog  = br ? alog_b : alog_f;
  const float* Dp    = br ? dd_b : dd_f;
  float Adn = -__expf(Alog[d*16 + n]);
  float Dd  = Dp[d];
  float h = 0.f;
  __shared__ float dC[16][17], xC[16][17], bC[16][17], cC[16][17], zC[16][17], yC[16][17];
  int li = tid >> 4, ci = tid & 15;
  for (int l0=0; l0<LL; l0+=16) {
    dC[li][ci] = delta[(long)(l0+li)*DIx + d0+ci];
    xC[li][ci] = xt[(long)(l0+li)*DIx + d0+ci];
    bC[li][ci] = xdbl[(long)(l0+li)*96 + 64 + ci];
    cC[li][ci] = xdbl[(long)(l0+li)*96 + 80 + ci];
    int gl = br ? (LL-1-(l0+li)) : (l0+li);
    zC[li][ci] = g_z_t[((long)b*LL + gl)*DIx + d0+ci];
    __syncthreads();
    for (int ll=0; ll<16; ++ll) {
      float dlt = dC[ll][dl];
      float xv  = xC[ll][dl];
      float dA  = __expf(dlt * Adn);
      float dBu = dlt * bC[ll][n] * xv;
      h = fmaf(h, dA, dBu);
      float c = h * cC[ll][n];
      c += __shfl_xor(c, 1); c += __shfl_xor(c, 2);
      c += __shfl_xor(c, 4); c += __shfl_xor(c, 8);
      if (n == 0) {
        float y = c + Dd * xv;
        yC[ll][dl] = y * siluf(zC[ll][dl]);
      }
    }
    __syncthreads();
    outp[(long)(l0+li)*DIx + d0+ci] = yC[li][ci];
  }
}

// ---------------- Stockham radix-2 FFT in LDS ----------------
template<int N, bool INV>
__device__ float2* fft_lds(float2* b0, float2* b1, int tid)
{
  constexpr int LOGN = (N==1024) ? 10 : 11;
  float2* in = b0; float2* out = b1;
  for (int st=0; st<LOGN; ++st) {
    int s = 1 << st;
    float invn = 1.f / (float)(N >> st);
    #pragma unroll
    for (int i=0; i<N/512; ++i) {
      int j = tid + 256*i;
      int p = j >> st;
      int q = j & (s-1);
      float ang = (INV ? 6.283185307179586f : -6.283185307179586f) * (float)p * invn;
      float sn, cs;
      __sincosf(ang, &sn, &cs);
      float2 a = in[j];
      float2 bb = in[j + N/2];
      float2 sum = make_float2(a.x+bb.x, a.y+bb.y);
      float2 dif = make_float2(a.x-bb.x, a.y-bb.y);
      float2 tw  = make_float2(dif.x*cs - dif.y*sn, dif.x*sn + dif.y*cs);
      int i0 = q + (p << (st+1));
      out[i0] = sum;
      out[i0 + s] = tw;
    }
    __syncthreads();
    float2* t = in; in = out; out = t;
  }
  return in;
}

__global__ __launch_bounds__(256) void fft_l_fwd() {
  __shared__ float2 b0[1024], b1[1024];
  int d = blockIdx.x, b = blockIdx.y, tid = threadIdx.x;
  const float* src = g_xz + ((long)b*E2 + d)*LL;
  #pragma unroll
  for (int i=0;i<4;i++) { int l = tid + 256*i; b0[l] = make_float2(src[l], 0.f); }
  __syncthreads();
  float2* res = fft_lds<1024,false>(b0, b1, tid);
  float2* dst = g_fftA + (long)b*LL*DIx;
  #pragma unroll
  for (int i=0;i<4;i++) { int l = tid + 256*i; dst[(long)l*DIx + d] = res[l]; }
}

__global__ __launch_bounds__(256) void fft_d_fwd() {
  __shared__ float2 b0[2048], b1[2048];
  int l = blockIdx.x, b = blockIdx.y, tid = threadIdx.x;
  const float2* src = g_fftA + ((long)b*LL + l)*DIx;
  #pragma unroll
  for (int i=0;i<8;i++) { int d = tid + 256*i; b0[d] = src[d]; }
  __syncthreads();
  float2* res = fft_lds<2048,false>(b0, b1, tid);
  bf16* dst = g_xc + ((long)b*LL + l)*E2;
  #pragma unroll
  for (int i=0;i<8;i++) {
    int d = tid + 256*i;
    float2 v = res[d];
    dst[d]       = __float2bfloat16(v.x);
    dst[DIx + d] = __float2bfloat16(v.y);
  }
}

__global__ __launch_bounds__(256) void fft_l_inv(const float* fbias) {
  __shared__ float2 b0[1024], b1[1024];
  int d = blockIdx.x, b = blockIdx.y, tid = threadIdx.x;
  const float* re = g_conv_out + ((long)b*E2 + d)*LL;
  const float* im = g_conv_out + ((long)b*E2 + DIx + d)*LL;
  float br_ = fbias[d], bi_ = fbias[DIx + d];
  #pragma unroll
  for (int i=0;i<4;i++) {
    int l = tid + 256*i;
    float r = re[l] + br_;
    float m = im[l] + bi_;
    b0[l] = make_float2(siluf(r), siluf(m));
  }
  __syncthreads();
  float2* res = fft_lds<1024,true>(b0, b1, tid);
  float2* dst = g_fftA + (long)b*LL*DIx;
  const float sc = 1.f/1024.f;
  #pragma unroll
  for (int i=0;i<4;i++) {
    int l = tid + 256*i;
    float2 v = res[l];
    dst[(long)l*DIx + d] = make_float2(v.x*sc, v.y*sc);
  }
}

__global__ __launch_bounds__(256) void fft_d_inv() {
  __shared__ float2 b0[2048], b1[2048];
  int l = blockIdx.x, b = blockIdx.y, tid = threadIdx.x;
  const float2* src = g_fftA + ((long)b*LL + l)*DIx;
  #pragma unroll
  for (int i=0;i<8;i++) { int d = tid + 256*i; b0[d] = src[d]; }
  __syncthreads();
  float2* res = fft_lds<2048,true>(b0, b1, tid);
  float* dst = g_v + ((long)b*LL + l)*DIx;
  const float sc = 1.f/2048.f;
  #pragma unroll
  for (int i=0;i<8;i++) {
    int d = tid + 256*i;
    float2 v = res[d];
    dst[d] = sqrtf(v.x*v.x + v.y*v.y) * sc * g_zmax[b*DIx + d];
  }
}

// ---------------- z_out = |max_l silu(z)| ----------------
__global__ __launch_bounds__(256) void zmax_kernel() {
  int wid = blockIdx.x*4 + (threadIdx.x>>6);
  int lane = threadIdx.x & 63;
  int b = wid >> 11, d = wid & 2047;
  const float* z = g_xz + ((long)b*E2 + DIx + d)*LL;
  float m = -1e30f;
  for (int i=lane; i<LL; i+=64) m = fmaxf(m, siluf(z[i]));
  #pragma unroll
  for (int o=32; o>=1; o>>=1) m = fmaxf(m, __shfl_xor(m, o));
  if (lane == 0) g_zmax[b*DIx + d] = fabsf(m);
}

// ---------------- mean/var over l of v ----------------
__global__ __launch_bounds__(256) void musig_kernel() {
  int d = blockIdx.x*256 + threadIdx.x;
  int b = blockIdx.y;
  const float* v = g_v + (long)b*LL*DIx + d;
  float s=0.f, s2=0.f;
  for (int l=0;l<LL;l++) { float x = v[(long)l*DIx]; s += x; s2 += x*x; }
  float mu = s * (1.f/LL);
  float var = s2 * (1.f/LL) - mu*mu;
  g_mu[b*DIx+d] = mu;
  g_rsig[b*DIx+d] = rsqrtf(var + 1e-5f);
}

// ---------------- combine branches -> y bf16 (b,l,d) ----------------
__global__ __launch_bounds__(256) void combine_kernel() {
  long total = (long)BB*LL*DIx;
  for (long idx = (long)blockIdx.x*256 + threadIdx.x; idx < total; idx += (long)gridDim.x*256) {
    int d = (int)(idx & (DIx-1));
    long bl = idx >> 11;
    int l = (int)(bl & (LL-1));
    int b = (int)(bl >> 10);
    float of = g_out_f[idx];
    float ob = g_out_b[(((long)b*LL) + (LL-1-l))*DIx + d];   // un-reverse bwd branch
    float vv = g_v[idx];
    float y = of + ob + (vv - g_mu[b*DIx+d]) * g_rsig[b*DIx+d];
    g_y_bf16[idx] = __float2bfloat16(y);
  }
}

extern "C" void kernel_launch(void* const* d_in, const int* in_sizes, int n_in,
                              void* d_out, int out_size, void* d_ws, size_t ws_size,
                              hipStream_t stream) {
  const float* hs    = (const float*)d_in[0];
  const float* winw  = (const float*)d_in[1];
  const float* cw_f  = (const float*)d_in[2];
  const float* cb_f  = (const float*)d_in[3];
  const float* wxp_f = (const float*)d_in[4];
  const float* wdt_f = (const float*)d_in[5];
  const float* dtb_f = (const float*)d_in[6];
  const float* alog_f= (const float*)d_in[7];
  const float* dd_f  = (const float*)d_in[8];
  const float* cw_b  = (const float*)d_in[9];
  const float* cb_b  = (const float*)d_in[10];
  const float* wxp_b = (const float*)d_in[11];
  const float* wdt_b = (const float*)d_in[12];
  const float* dtb_b = (const float*)d_in[13];
  const float* alog_b= (const float*)d_in[14];
  const float* dd_b  = (const float*)d_in[15];
  const float* woutw = (const float*)d_in[16];
  const float* wcw   = (const float*)d_in[17];
  const float* wcb   = (const float*)d_in[18];
  float* out = (float*)d_out;

  cast_all<<<2048, 256, 0, stream>>>(hs, winw, woutw, wxp_f, wxp_b, wdt_f, wdt_b);
  repack_wc<<<8192, 256, 0, stream>>>(wcw);

  // xz = in_proj
  gemm_nt<0><<<dim3(8,32,2), 256, 0, stream>>>(nullptr, nullptr);

  // depthwise conv + silu (fwd, bwd) and z transpose
  k3_kernel<<<dim3(16,32,6), 256, 0, stream>>>(cw_f, cb_f, cw_b, cb_b);

  // x_proj (split-K=16 with atomics)
  zero_xdbl<<<192, 256, 0, stream>>>();
  gemm_nt<1><<<dim3(1,8,32), 256, 0, stream>>>(nullptr, nullptr);
  gemm_nt<2><<<dim3(1,8,32), 256, 0, stream>>>(nullptr, nullptr);
  cast_xdbl<<<192, 256, 0, stream>>>();

  // dt_proj + softplus(bias) fused
  gemm_nt<3><<<dim3(16,8,2), 256, 0, stream>>>(nullptr, dtb_f);
  gemm_nt<4><<<dim3(16,8,2), 256, 0, stream>>>(nullptr, dtb_b);

  // selective scan (both branches), gated by silu(z)
  scan_kernel<<<dim3(128,2,2), 256, 0, stream>>>(alog_f, dd_f, alog_b, dd_b);

  // FFT branch
  fft_l_fwd<<<dim3(2048,2), 256, 0, stream>>>();
  fft_d_fwd<<<dim3(1024,2), 256, 0, stream>>>();
  gemm_nt<5><<<dim3(8,32,2), 256, 0, stream>>>(nullptr, nullptr);   // 343 GFLOP conv
  zmax_kernel<<<1024, 256, 0, stream>>>();
  fft_l_inv<<<dim3(2048,2), 256, 0, stream>>>(wcb);
  fft_d_inv<<<dim3(1024,2), 256, 0, stream>>>();
  musig_kernel<<<dim3(8,2), 256, 0, stream>>>();

  // combine + out_proj
  combine_kernel<<<4096, 256, 0, stream>>>();
  gemm_nt<6><<<dim3(8,8,2), 256, 0, stream>>>(out, nullptr);
}

// Round 3
// 2001.055 us; speedup vs baseline: 1.3166x; 1.3166x over previous
//
#include <hip/hip_runtime.h>
#include <hip/hip_bf16.h>

typedef __hip_bfloat16 bf16;
typedef __attribute__((ext_vector_type(8))) short bf16x8;
typedef __attribute__((ext_vector_type(4))) float f32x4;

// ---- dims ----
#define BB   2
#define LL   1024
#define DMm  1024
#define DIx  2048
#define E2   4096
#define DRr  64
#define XCR  1040   // padded rows per batch for g_xc (2 halo + slack)

// ---- workspace: static device globals ----
__device__ __align__(16) bf16  g_hs_bf16[(long)BB*LL*DMm];        // (b,l,d) bf16
__device__ __align__(16) bf16  g_win_bf16[(long)E2*DMm];          // (e,d)
__device__ __align__(16) float g_xz[(long)BB*E2*LL];              // (b,e,l) fp32
__device__ __align__(16) float g_xf_t[(long)BB*LL*DIx];           // fwd conv'd x, (b,l,d)
__device__ __align__(16) float g_xb_t[(long)BB*LL*DIx];           // bwd conv'd x, (b,l',d)
__device__ __align__(16) float g_z_t[(long)BB*LL*DIx];            // z transposed (b,l,d)
__device__ __align__(16) bf16  g_xf_bf16[(long)BB*LL*DIx];
__device__ __align__(16) bf16  g_xb_bf16[(long)BB*LL*DIx];
__device__ __align__(16) bf16  g_wxp_f[96*DIx], g_wxp_b[96*DIx];
__device__ __align__(16) float g_xdbl_f[(long)BB*LL*96], g_xdbl_b[(long)BB*LL*96];
__device__ __align__(16) bf16  g_xdbl_f_bf16[(long)BB*LL*96], g_xdbl_b_bf16[(long)BB*LL*96];
__device__ __align__(16) bf16  g_wdt_f[DIx*DRr], g_wdt_b[DIx*DRr];
__device__ __align__(16) float g_delta_f[(long)BB*LL*DIx], g_delta_b[(long)BB*LL*DIx];
__device__ __align__(16) float g_out_f[(long)BB*LL*DIx], g_out_b[(long)BB*LL*DIx];
__device__ __align__(16) float2 g_fftA[(long)BB*LL*DIx];          // (b,l,d) complex
__device__ __align__(16) bf16  g_xc[(long)BB*XCR*E2];             // conv input, padded rows (b, l+2, ch)
__device__ __align__(16) bf16  g_wc[(long)5*E2*E2];               // conv W repacked [t][o][i] bf16
__device__ __align__(16) float g_conv_out[(long)BB*E2*LL];        // (b,o,l)
__device__ __align__(16) float g_v[(long)BB*LL*DIx];              // (b,l,d)
__device__ float g_zmax[BB*DIx], g_mu[BB*DIx], g_rsig[BB*DIx];
__device__ __align__(16) bf16  g_y_bf16[(long)BB*LL*DIx];         // (b,l,d)
__device__ __align__(16) bf16  g_wout_bf16[(long)DMm*DIx];

__device__ __forceinline__ float siluf(float x) { return x / (1.f + __expf(-x)); }

__device__ __forceinline__ void gl_lds16(const void* g, void* l) {
  __builtin_amdgcn_global_load_lds(
      (const __attribute__((address_space(1))) unsigned int*)g,
      (__attribute__((address_space(3))) unsigned int*)l, 16, 0, 0);
}

// ---------------- casts ----------------
__global__ void cast_all(const float* hs, const float* win, const float* wout,
                         const float* wxpf, const float* wxpb,
                         const float* wdtf, const float* wdtb)
{
  long t0 = (long)blockIdx.x*256 + threadIdx.x;
  long st = (long)gridDim.x*256;
  for (long i=t0; i<(long)BB*LL*DMm; i+=st) g_hs_bf16[i]  = __float2bfloat16(hs[i]);
  for (long i=t0; i<(long)E2*DMm;    i+=st) g_win_bf16[i] = __float2bfloat16(win[i]);
  for (long i=t0; i<(long)DMm*DIx;   i+=st) g_wout_bf16[i]= __float2bfloat16(wout[i]);
  for (long i=t0; i<(long)96*DIx;    i+=st) { g_wxp_f[i]=__float2bfloat16(wxpf[i]); g_wxp_b[i]=__float2bfloat16(wxpb[i]); }
  for (long i=t0; i<(long)DIx*DRr;   i+=st) { g_wdt_f[i]=__float2bfloat16(wdtf[i]); g_wdt_b[i]=__float2bfloat16(wdtb[i]); }
}

// (o,i,t) fp32 -> [t][o][i] bf16, coalesced via LDS
__global__ __launch_bounds__(256) void repack_wc(const float* wc)
{
  __shared__ float s[1280];
  const long NM = (long)E2*E2;
  long base = (long)blockIdx.x * 256;           // (o,i) pair base
  const float* src = wc + base*5;
  #pragma unroll
  for (int j=0;j<5;j++) s[threadIdx.x + 256*j] = src[threadIdx.x + 256*j];
  __syncthreads();
  #pragma unroll
  for (int t=0;t<5;t++)
    g_wc[(long)t*NM + base + threadIdx.x] = __float2bfloat16(s[threadIdx.x*5 + t]);
}

// zero halo + slack rows of padded g_xc
__global__ void zero_xc_pad() {
  int r = blockIdx.y;                  // 0..15
  int row = (r < 2) ? r : (1024 + r);  // rows {0,1} U {1026..1039}
  int b = blockIdx.z;
  long base = ((long)b*XCR + row)*E2;
  g_xc[base + blockIdx.x*256 + threadIdx.x] = __float2bfloat16(0.f);
}

__global__ void zero_xdbl() {
  long n = (long)BB*LL*96;
  for (long i=(long)blockIdx.x*256+threadIdx.x; i<n; i+=(long)gridDim.x*256) { g_xdbl_f[i]=0.f; g_xdbl_b[i]=0.f; }
}
__global__ void cast_xdbl() {
  long n = (long)BB*LL*96;
  for (long i=(long)blockIdx.x*256+threadIdx.x; i<n; i+=(long)gridDim.x*256) {
    g_xdbl_f_bf16[i]=__float2bfloat16(g_xdbl_f[i]);
    g_xdbl_b_bf16[i]=__float2bfloat16(g_xdbl_b[i]);
  }
}

// ---------------- fast NT MFMA GEMM (m97 structure + swizzled LDS) ----------------
// IDs: 0 = in_proj (M=4096 e, N=2048 b*l, K=1024)
//      5 = freq-conv (M=4096 o, N=2048 b*l, K=5 taps x 4096, B from padded g_xc)
//      6 = out_proj (M=2048 b*l, N=1024 o, K=2048)
template<int ID>
__global__ __launch_bounds__(256) void gemm_fast(float* Cext)
{
  constexpr int M    = (ID==6) ? 2048 : 4096;
  constexpr int K    = (ID==0) ? 1024 : (ID==5) ? 4096 : 2048;
  constexpr int TAPS = (ID==5) ? 5 : 1;
  constexpr int PAD  = (ID==5) ? 2 : 0;
  constexpr int BCH  = (ID==5) ? 17 : 16;   // B chunks of 8 rows (halo window for conv)

  __shared__ bf16 As[128*64];
  __shared__ bf16 Bs[BCH*8*64];

  const int nwg  = gridDim.x * gridDim.y;
  const int orig = blockIdx.y * gridDim.x + blockIdx.x;
  const int swz  = (orig & 7) * (nwg >> 3) + (orig >> 3);   // XCD-chunked (nwg%8==0)
  const int mt = swz / gridDim.x, nt = swz - mt*gridDim.x;
  const int m0 = mt*128, n0 = nt*128;

  const int tid = threadIdx.x, wv = tid>>6, ln = tid&63;
  const int lr = ln&15, lkb = (ln>>4)<<4;          // fragment row, k-byte offset
  const int wrr = (wv>>1)*64, wcc = (wv&1)*64;
  const int srow = ln>>3;                          // staging: row within 8-row chunk
  const int scol = ((ln&7) ^ srow)*8;              // pre-swizzled global col (elements)

  const bf16* Ab;
  const bf16* Brow;
  if constexpr (ID==0) { Ab = g_win_bf16; Brow = g_hs_bf16 + (long)n0*K; }
  if constexpr (ID==5) { Ab = g_wc;       Brow = g_xc + ((long)(n0>>10)*XCR + (n0&1023))*K; }
  if constexpr (ID==6) { Ab = g_y_bf16;   Brow = g_wout_bf16 + (long)n0*K; }

  f32x4 acc[4][4];
  #pragma unroll
  for (int i=0;i<4;i++)
    #pragma unroll
    for (int j=0;j<4;j++) acc[i][j] = (f32x4){0.f,0.f,0.f,0.f};

  for (int k0=0; k0<K; k0+=64) {
    __syncthreads();                               // prev compute done before overwrite
    // stage B window (once per K-step; serves all taps)
    for (int c=wv; c<BCH; c+=4)
      gl_lds16(Brow + (long)(c*8 + srow)*K + k0 + scol, (char*)Bs + c*1024);
    for (int tap=0; tap<TAPS; ++tap) {
      const bf16* At = Ab + (long)tap*M*K + (long)m0*K;
      #pragma unroll
      for (int q=0;q<4;q++) {
        int c = wv*4 + q;
        gl_lds16(At + (long)(c*8 + srow)*K + k0 + scol, (char*)As + c*1024);
      }
      __syncthreads();                             // vmcnt drained by compiler
      #pragma unroll
      for (int kk=0; kk<2; ++kk) {
        bf16x8 af[4], bfr[4];
        #pragma unroll
        for (int i=0;i<4;i++) {
          int ar = wrr + i*16 + lr;
          af[i]  = *(const bf16x8*)((const char*)As + ar*128 + ((kk*64 + lkb) ^ ((ar&7)<<4)));
          int br = wcc + i*16 + lr + PAD + ((TAPS>1) ? (tap-2) : 0);
          bfr[i] = *(const bf16x8*)((const char*)Bs + br*128 + ((kk*64 + lkb) ^ ((br&7)<<4)));
        }
        #pragma unroll
        for (int i=0;i<4;i++)
          #pragma unroll
          for (int j=0;j<4;j++)
            acc[i][j] = __builtin_amdgcn_mfma_f32_16x16x32_bf16(af[i], bfr[j], acc[i][j], 0,0,0);
      }
      if (tap+1 < TAPS) __syncthreads();           // before next A restage
    }
  }

  const int rg = (ln>>4)*4;   // C/D: col=lane&15, row=(lane>>4)*4+reg
  #pragma unroll
  for (int i=0;i<4;i++)
    #pragma unroll
    for (int j=0;j<4;j++)
      #pragma unroll
      for (int r=0;r<4;r++) {
        int m = m0 + wrr + i*16 + rg + r;
        int n = n0 + wcc + j*16 + lr;
        float v = acc[i][j][r];
        if constexpr (ID==0) g_xz[((long)(n>>10)*E2 + m)*LL + (n&1023)] = v;
        if constexpr (ID==5) g_conv_out[(long)(n>>10)*E2*LL + (long)m*LL + (n&1023)] = v;
        if constexpr (ID==6) Cext[(long)m*1024 + n] = v;
      }
}

// ---------------- small NT MFMA GEMM (IDs 1-4 only) ----------------
template<int ID>
__global__ __launch_bounds__(256) void gemm_nt(float* Cext, const float* bias)
{
  constexpr int M    = 1024;
  constexpr int N    = (ID==1||ID==2) ? 96 : 2048;
  constexpr int K    = (ID==1||ID==2) ? 2048 : 64;
  constexpr int LDA  = (ID==1||ID==2) ? 2048 : 96;
  constexpr int LDB  = (ID==1||ID==2) ? 2048 : 64;
  constexpr int LDC  = (ID==1||ID==2) ? 96 : 2048;
  constexpr int BROWS= (ID==1||ID==2) ? 96 : 2048;
  constexpr int SPLITK = (ID==1||ID==2) ? 16 : 1;
  constexpr bool SP  = (ID==3||ID==4);
  constexpr long SA  = (ID==3||ID==4) ? (long)LL*96 : (long)LL*DIx;
  constexpr long SC  = (ID==1||ID==2) ? (long)LL*96 : (long)LL*DIx;
  constexpr int KS   = K / SPLITK;

  const bf16* Abase; const bf16* Bbase; float* Cbase;
  if constexpr (ID==1) { Abase=g_xf_bf16; Bbase=g_wxp_f;   Cbase=g_xdbl_f; }
  else if constexpr (ID==2) { Abase=g_xb_bf16; Bbase=g_wxp_b;   Cbase=g_xdbl_b; }
  else if constexpr (ID==3) { Abase=g_xdbl_f_bf16; Bbase=g_wdt_f; Cbase=g_delta_f; }
  else                      { Abase=g_xdbl_b_bf16; Bbase=g_wdt_b; Cbase=g_delta_b; }

  const int tid  = threadIdx.x;
  const int zi   = blockIdx.z;
  const int bbat = zi / SPLITK;
  const int ksp  = zi % SPLITK;
  const bf16* Ab = Abase + (long)bbat*SA;
  const bf16* Bb = Bbase;
  float* Cb = Cbase + (long)bbat*SC;

  __shared__ bf16 As[128][72];
  __shared__ bf16 Bs[128][72];
  const int m0 = blockIdx.y*128, n0 = blockIdx.x*128;
  const int wave = tid>>6, lane = tid&63;
  const int wr = (wave>>1)*64, wc = (wave&1)*64;
  const int lr = lane&15, lk = (lane>>4)*8;
  const int srow = tid>>3, sch = (tid&7)*8;

  f32x4 acc[4][4];
  #pragma unroll
  for (int i=0;i<4;i++)
    #pragma unroll
    for (int j=0;j<4;j++) acc[i][j] = (f32x4){0.f,0.f,0.f,0.f};

  for (int kt=0; kt<KS; kt+=64) {
    const int k0 = ksp*KS + kt;
    __syncthreads();
    #pragma unroll
    for (int it=0; it<4; ++it) {
      int rr = srow + it*32;
      int mg = m0 + rr;
      uint4 va = make_uint4(0u,0u,0u,0u);
      if (mg < M) va = *(const uint4*)(Ab + (long)mg*LDA + k0 + sch);
      *(uint4*)&As[rr][sch] = va;
      int ng = n0 + rr;
      uint4 vb = make_uint4(0u,0u,0u,0u);
      if (ng < BROWS) vb = *(const uint4*)(Bb + (long)ng*LDB + k0 + sch);
      *(uint4*)&Bs[rr][sch] = vb;
    }
    __syncthreads();
    #pragma unroll
    for (int kk=0; kk<2; ++kk) {
      bf16x8 af[4], bfr[4];
      #pragma unroll
      for (int i=0;i<4;i++) {
        af[i]  = *(const bf16x8*)&As[wr + i*16 + lr][kk*32 + lk];
        bfr[i] = *(const bf16x8*)&Bs[wc + i*16 + lr][kk*32 + lk];
      }
      #pragma unroll
      for (int i=0;i<4;i++)
        #pragma unroll
        for (int j=0;j<4;j++)
          acc[i][j] = __builtin_amdgcn_mfma_f32_16x16x32_bf16(af[i], bfr[j], acc[i][j], 0,0,0);
    }
  }

  const int rg = (lane>>4)*4;
  #pragma unroll
  for (int i=0;i<4;i++) {
    #pragma unroll
    for (int j=0;j<4;j++) {
      int n = n0 + wc + j*16 + lr;
      if (n < N) {
        #pragma unroll
        for (int r=0;r<4;r++) {
          int m = m0 + wr + i*16 + rg + r;
          if (m < M) {
            float v = acc[i][j][r];
            if constexpr (SP) { v += bias[n]; v = (v > 20.f) ? v : log1pf(__expf(v)); }
            if constexpr (SPLITK > 1) atomicAdd(&Cb[(long)m*LDC + n], v);
            else Cb[(long)m*LDC + n] = v;
          }
        }
      }
    }
  }
}

// ---------------- depthwise causal conv + silu + transpose; also z transpose ----------------
__global__ __launch_bounds__(256) void k3_kernel(const float* cwf, const float* cbf,
                                                 const float* cwb, const float* cbb)
{
  int lt = blockIdx.x*64, dt = blockIdx.y*64;
  int b = blockIdx.z / 3, mode = blockIdx.z % 3;
  __shared__ float tile[64][68];
  int tid = threadIdx.x;
  for (int idx = tid; idx < 64*68; idx += 256) {
    int dl = idx / 68, c = idx % 68;
    float v = 0.f;
    if (c < 67) {
      int j = lt - 3 + c;
      if (j >= 0) {
        int gl = (mode==1) ? (LL-1-j) : j;
        int ch = (mode==2) ? (DIx + dt + dl) : (dt + dl);
        v = g_xz[((long)b*E2 + ch)*LL + gl];
      }
    }
    tile[dl][c] = v;
  }
  __syncthreads();
  int lloc = tid >> 2;
  int dseg = (tid & 3) * 16;
  long base = ((long)b*LL + (lt + lloc))*DIx + dt + dseg;
  if (mode == 2) {
    for (int jj=0; jj<16; ++jj) g_z_t[base+jj] = tile[dseg+jj][lloc+3];
  } else {
    const float* cw = mode ? cwb : cwf;
    const float* cb = mode ? cbb : cbf;
    float* xt = mode ? g_xb_t : g_xf_t;
    bf16*  xq = mode ? g_xb_bf16 : g_xf_bf16;
    for (int jj=0; jj<16; ++jj) {
      int dg = dt + dseg + jj;
      float a = cb[dg];
      #pragma unroll
      for (int t=0;t<4;t++) a = fmaf(cw[dg*4+t], tile[dseg+jj][lloc+t], a);
      float s = siluf(a);
      xt[base+jj] = s;
      xq[base+jj] = __float2bfloat16(s);
    }
  }
}

// ---------------- selective scan (both branches) ----------------
__global__ __launch_bounds__(256) void scan_kernel(const float* alog_f, const float* dd_f,
                                                   const float* alog_b, const float* dd_b)
{
  int br = blockIdx.z, b = blockIdx.y;
  int d0 = blockIdx.x * 16;
  int tid = threadIdx.x;
  int n = tid & 15, dl = tid >> 4;
  int d = d0 + dl;
  const float* delta = (br ? g_delta_b : g_delta_f) + (long)b*LL*DIx;
  const float* xt    = (br ? g_xb_t    : g_xf_t)    + (long)b*LL*DIx;
  const float* xdbl  = (br ? g_xdbl_b  : g_xdbl_f)  + (long)b*LL*96;
  float* outp        = (br ? g_out_b   : g_out_f)   + (long)b*LL*DIx;
  const float* Alog  = br ? alog_b : alog_f;
  const float* Dp    = br ? dd_b : dd_f;
  float Adn = -__expf(Alog[d*16 + n]);
  float Dd  = Dp[d];
  float h = 0.f;
  __shared__ float dC[16][17], xC[16][17], bC[16][17], cC[16][17], zC[16][17], yC[16][17];
  int li = tid >> 4, ci = tid & 15;
  for (int l0=0; l0<LL; l0+=16) {
    dC[li][ci] = delta[(long)(l0+li)*DIx + d0+ci];
    xC[li][ci] = xt[(long)(l0+li)*DIx + d0+ci];
    bC[li][ci] = xdbl[(long)(l0+li)*96 + 64 + ci];
    cC[li][ci] = xdbl[(long)(l0+li)*96 + 80 + ci];
    int gl = br ? (LL-1-(l0+li)) : (l0+li);
    zC[li][ci] = g_z_t[((long)b*LL + gl)*DIx + d0+ci];
    __syncthreads();
    for (int ll=0; ll<16; ++ll) {
      float dlt = dC[ll][dl];
      float xv  = xC[ll][dl];
      float dA  = __expf(dlt * Adn);
      float dBu = dlt * bC[ll][n] * xv;
      h = fmaf(h, dA, dBu);
      float c = h * cC[ll][n];
      c += __shfl_xor(c, 1); c += __shfl_xor(c, 2);
      c += __shfl_xor(c, 4); c += __shfl_xor(c, 8);
      if (n == 0) {
        float y = c + Dd * xv;
        yC[ll][dl] = y * siluf(zC[ll][dl]);
      }
    }
    __syncthreads();
    outp[(long)(l0+li)*DIx + d0+ci] = yC[li][ci];
  }
}

// ---------------- Stockham radix-2 FFT in LDS ----------------
template<int N, bool INV>
__device__ float2* fft_lds(float2* b0, float2* b1, int tid)
{
  constexpr int LOGN = (N==1024) ? 10 : 11;
  float2* in = b0; float2* out = b1;
  for (int st=0; st<LOGN; ++st) {
    int s = 1 << st;
    float invn = 1.f / (float)(N >> st);
    #pragma unroll
    for (int i=0; i<N/512; ++i) {
      int j = tid + 256*i;
      int p = j >> st;
      int q = j & (s-1);
      float ang = (INV ? 6.283185307179586f : -6.283185307179586f) * (float)p * invn;
      float sn, cs;
      __sincosf(ang, &sn, &cs);
      float2 a = in[j];
      float2 bb = in[j + N/2];
      float2 sum = make_float2(a.x+bb.x, a.y+bb.y);
      float2 dif = make_float2(a.x-bb.x, a.y-bb.y);
      float2 tw  = make_float2(dif.x*cs - dif.y*sn, dif.x*sn + dif.y*cs);
      int i0 = q + (p << (st+1));
      out[i0] = sum;
      out[i0 + s] = tw;
    }
    __syncthreads();
    float2* t = in; in = out; out = t;
  }
  return in;
}

__global__ __launch_bounds__(256) void fft_l_fwd() {
  __shared__ float2 b0[1024], b1[1024];
  int d = blockIdx.x, b = blockIdx.y, tid = threadIdx.x;
  const float* src = g_xz + ((long)b*E2 + d)*LL;
  #pragma unroll
  for (int i=0;i<4;i++) { int l = tid + 256*i; b0[l] = make_float2(src[l], 0.f); }
  __syncthreads();
  float2* res = fft_lds<1024,false>(b0, b1, tid);
  float2* dst = g_fftA + (long)b*LL*DIx;
  #pragma unroll
  for (int i=0;i<4;i++) { int l = tid + 256*i; dst[(long)l*DIx + d] = res[l]; }
}

__global__ __launch_bounds__(256) void fft_d_fwd() {
  __shared__ float2 b0[2048], b1[2048];
  int l = blockIdx.x, b = blockIdx.y, tid = threadIdx.x;
  const float2* src = g_fftA + ((long)b*LL + l)*DIx;
  #pragma unroll
  for (int i=0;i<8;i++) { int d = tid + 256*i; b0[d] = src[d]; }
  __syncthreads();
  float2* res = fft_lds<2048,false>(b0, b1, tid);
  bf16* dst = g_xc + ((long)b*XCR + l + 2)*E2;     // padded row l+2
  #pragma unroll
  for (int i=0;i<8;i++) {
    int d = tid + 256*i;
    float2 v = res[d];
    dst[d]       = __float2bfloat16(v.x);
    dst[DIx + d] = __float2bfloat16(v.y);
  }
}

__global__ __launch_bounds__(256) void fft_l_inv(const float* fbias) {
  __shared__ float2 b0[1024], b1[1024];
  int d = blockIdx.x, b = blockIdx.y, tid = threadIdx.x;
  const float* re = g_conv_out + ((long)b*E2 + d)*LL;
  const float* im = g_conv_out + ((long)b*E2 + DIx + d)*LL;
  float br_ = fbias[d], bi_ = fbias[DIx + d];
  #pragma unroll
  for (int i=0;i<4;i++) {
    int l = tid + 256*i;
    float r = re[l] + br_;
    float m = im[l] + bi_;
    b0[l] = make_float2(siluf(r), siluf(m));
  }
  __syncthreads();
  float2* res = fft_lds<1024,true>(b0, b1, tid);
  float2* dst = g_fftA + (long)b*LL*DIx;
  const float sc = 1.f/1024.f;
  #pragma unroll
  for (int i=0;i<4;i++) {
    int l = tid + 256*i;
    float2 v = res[l];
    dst[(long)l*DIx + d] = make_float2(v.x*sc, v.y*sc);
  }
}

__global__ __launch_bounds__(256) void fft_d_inv() {
  __shared__ float2 b0[2048], b1[2048];
  int l = blockIdx.x, b = blockIdx.y, tid = threadIdx.x;
  const float2* src = g_fftA + ((long)b*LL + l)*DIx;
  #pragma unroll
  for (int i=0;i<8;i++) { int d = tid + 256*i; b0[d] = src[d]; }
  __syncthreads();
  float2* res = fft_lds<2048,true>(b0, b1, tid);
  float* dst = g_v + ((long)b*LL + l)*DIx;
  const float sc = 1.f/2048.f;
  #pragma unroll
  for (int i=0;i<8;i++) {
    int d = tid + 256*i;
    float2 v = res[d];
    dst[d] = sqrtf(v.x*v.x + v.y*v.y) * sc * g_zmax[b*DIx + d];
  }
}

// ---------------- z_out = |max_l silu(z)| ----------------
__global__ __launch_bounds__(256) void zmax_kernel() {
  int wid = blockIdx.x*4 + (threadIdx.x>>6);
  int lane = threadIdx.x & 63;
  int b = wid >> 11, d = wid & 2047;
  const float* z = g_xz + ((long)b*E2 + DIx + d)*LL;
  float m = -1e30f;
  for (int i=lane; i<LL; i+=64) m = fmaxf(m, siluf(z[i]));
  #pragma unroll
  for (int o=32; o>=1; o>>=1) m = fmaxf(m, __shfl_xor(m, o));
  if (lane == 0) g_zmax[b*DIx + d] = fabsf(m);
}

// ---------------- mean/var over l of v ----------------
__global__ __launch_bounds__(256) void musig_kernel() {
  int d = blockIdx.x*256 + threadIdx.x;
  int b = blockIdx.y;
  const float* v = g_v + (long)b*LL*DIx + d;
  float s=0.f, s2=0.f;
  for (int l=0;l<LL;l++) { float x = v[(long)l*DIx]; s += x; s2 += x*x; }
  float mu = s * (1.f/LL);
  float var = s2 * (1.f/LL) - mu*mu;
  g_mu[b*DIx+d] = mu;
  g_rsig[b*DIx+d] = rsqrtf(var + 1e-5f);
}

// ---------------- combine branches -> y bf16 (b,l,d) ----------------
__global__ __launch_bounds__(256) void combine_kernel() {
  long total = (long)BB*LL*DIx;
  for (long idx = (long)blockIdx.x*256 + threadIdx.x; idx < total; idx += (long)gridDim.x*256) {
    int d = (int)(idx & (DIx-1));
    long bl = idx >> 11;
    int l = (int)(bl & (LL-1));
    int b = (int)(bl >> 10);
    float of = g_out_f[idx];
    float ob = g_out_b[(((long)b*LL) + (LL-1-l))*DIx + d];
    float vv = g_v[idx];
    float y = of + ob + (vv - g_mu[b*DIx+d]) * g_rsig[b*DIx+d];
    g_y_bf16[idx] = __float2bfloat16(y);
  }
}

extern "C" void kernel_launch(void* const* d_in, const int* in_sizes, int n_in,
                              void* d_out, int out_size, void* d_ws, size_t ws_size,
                              hipStream_t stream) {
  const float* hs    = (const float*)d_in[0];
  const float* winw  = (const float*)d_in[1];
  const float* cw_f  = (const float*)d_in[2];
  const float* cb_f  = (const float*)d_in[3];
  const float* wxp_f = (const float*)d_in[4];
  const float* wdt_f = (const float*)d_in[5];
  const float* dtb_f = (const float*)d_in[6];
  const float* alog_f= (const float*)d_in[7];
  const float* dd_f  = (const float*)d_in[8];
  const float* cw_b  = (const float*)d_in[9];
  const float* cb_b  = (const float*)d_in[10];
  const float* wxp_b = (const float*)d_in[11];
  const float* wdt_b = (const float*)d_in[12];
  const float* dtb_b = (const float*)d_in[13];
  const float* alog_b= (const float*)d_in[14];
  const float* dd_b  = (const float*)d_in[15];
  const float* woutw = (const float*)d_in[16];
  const float* wcw   = (const float*)d_in[17];
  const float* wcb   = (const float*)d_in[18];
  float* out = (float*)d_out;

  cast_all<<<2048, 256, 0, stream>>>(hs, winw, woutw, wxp_f, wxp_b, wdt_f, wdt_b);
  repack_wc<<<65536, 256, 0, stream>>>(wcw);
  zero_xc_pad<<<dim3(16,16,2), 256, 0, stream>>>();

  // xz = in_proj  (M=4096, N=2048, K=1024)
  gemm_fast<0><<<dim3(16,32), 256, 0, stream>>>(nullptr);

  // depthwise conv + silu (fwd, bwd) and z transpose
  k3_kernel<<<dim3(16,32,6), 256, 0, stream>>>(cw_f, cb_f, cw_b, cb_b);

  // x_proj (split-K=16 with atomics)
  zero_xdbl<<<192, 256, 0, stream>>>();
  gemm_nt<1><<<dim3(1,8,32), 256, 0, stream>>>(nullptr, nullptr);
  gemm_nt<2><<<dim3(1,8,32), 256, 0, stream>>>(nullptr, nullptr);
  cast_xdbl<<<192, 256, 0, stream>>>();

  // dt_proj + softplus(bias) fused
  gemm_nt<3><<<dim3(16,8,2), 256, 0, stream>>>(nullptr, dtb_f);
  gemm_nt<4><<<dim3(16,8,2), 256, 0, stream>>>(nullptr, dtb_b);

  // selective scan (both branches), gated by silu(z)
  scan_kernel<<<dim3(128,2,2), 256, 0, stream>>>(alog_f, dd_f, alog_b, dd_b);

  // FFT branch
  fft_l_fwd<<<dim3(2048,2), 256, 0, stream>>>();
  fft_d_fwd<<<dim3(1024,2), 256, 0, stream>>>();
  gemm_fast<5><<<dim3(16,32), 256, 0, stream>>>(nullptr);   // 343 GFLOP conv
  zmax_kernel<<<1024, 256, 0, stream>>>();
  fft_l_inv<<<dim3(2048,2), 256, 0, stream>>>(wcb);
  fft_d_inv<<<dim3(1024,2), 256, 0, stream>>>();
  musig_kernel<<<dim3(8,2), 256, 0, stream>>>();

  // combine + out_proj
  combine_kernel<<<4096, 256, 0, stream>>>();
  gemm_fast<6><<<dim3(8,16), 256, 0, stream>>>(out);
}